// Round 1
// baseline (868.151 us; speedup 1.0000x reference)
//
#include <hip/hip_runtime.h>
#include <cstddef>

#define B_ 4
#define C_ 256
#define N_ 4096
#define QK_ELEMS (B_ * 64 * N_)          /* 1048576 : raw/activated y1(0..31) + y2(32..63), layout [b][64][N] */
#define D_ELEMS  (B_ * C_ * N_)          /* 4194304 : y3 / d, layout [b][256][N] */
#define SC_OFF   (QK_ELEMS + D_ELEMS)    /* 5242880 : 320 folded scales */
#define BI_OFF   (SC_OFF + 320)          /* 320 folded biases */

// ---------------------------------------------------------------------------
// Kernel 1: y = w @ x for all 320 output channels (raw, pre-BN).
// Grid: (256 column tiles of 64, 5 row tiles of 64). Block 256, 4x4/thread.
// ---------------------------------------------------------------------------
__global__ __launch_bounds__(256) void ygemm_kernel(
    const float* __restrict__ x, const float* __restrict__ w1,
    const float* __restrict__ w2, const float* __restrict__ w3,
    float* __restrict__ ws)
{
    __shared__ __align__(16) float Ws[32][68];
    __shared__ __align__(16) float Xs[32][68];
    const int colTile = blockIdx.x;
    const int by = blockIdx.y;
    const int b = (colTile << 6) / N_;
    const int n0 = (colTile << 6) & (N_ - 1);
    const int obase = by << 6;
    const int tx = threadIdx.x & 15, ty = threadIdx.x >> 4;
    const int ckl = threadIdx.x & 31;   // W loader: col within 32-chunk
    const int olb = threadIdx.x >> 5;   // W loader: row base (0..7)
    const int nl  = threadIdx.x & 63;   // X loader: col (0..63)
    const int clb = threadIdx.x >> 6;   // X loader: row base (0..3)
    float acc[4][4] = {};

    for (int cb = 0; cb < C_; cb += 32) {
#pragma unroll
        for (int i = 0; i < 8; ++i) {
            int ol = olb + (i << 3);
            int og = obase + ol;
            const float* wr = (og < 32) ? (w1 + og * C_)
                              : (og < 64) ? (w2 + (og - 32) * C_)
                                          : (w3 + (og - 64) * C_);
            Ws[ckl][ol] = wr[cb + ckl];
        }
#pragma unroll
        for (int i = 0; i < 8; ++i) {
            int cl = clb + (i << 2);
            Xs[cl][nl] = x[((size_t)b * C_ + cb + cl) * N_ + n0 + nl];
        }
        __syncthreads();
#pragma unroll
        for (int kk = 0; kk < 32; ++kk) {
            float4 a4 = *(const float4*)&Ws[kk][ty << 2];
            float4 b4 = *(const float4*)&Xs[kk][tx << 2];
            float av[4] = {a4.x, a4.y, a4.z, a4.w};
            float bv[4] = {b4.x, b4.y, b4.z, b4.w};
#pragma unroll
            for (int i = 0; i < 4; ++i)
#pragma unroll
                for (int j = 0; j < 4; ++j)
                    acc[i][j] += av[i] * bv[j];
        }
        __syncthreads();
    }
#pragma unroll
    for (int i = 0; i < 4; ++i) {
        int og = obase + (ty << 2) + i;
        float4 v = {acc[i][0], acc[i][1], acc[i][2], acc[i][3]};
        size_t idx;
        if (og < 64) idx = ((size_t)b * 64 + og) * N_ + n0 + (tx << 2);
        else idx = (size_t)QK_ELEMS + ((size_t)b * C_ + (og - 64)) * N_ + n0 + (tx << 2);
        *(float4*)&ws[idx] = v;
    }
}

// ---------------------------------------------------------------------------
// Kernel 2: per-channel mean/var over (B,N) -> folded affine sc,bi.
// Grid: 320 blocks (ch 0..31 -> w1/g1/b1, 32..63 -> w2, 64..319 -> w3).
// ---------------------------------------------------------------------------
__global__ __launch_bounds__(256) void stats_kernel(
    const float* __restrict__ ws_r,
    const float* __restrict__ g1, const float* __restrict__ b1,
    const float* __restrict__ g2, const float* __restrict__ b2,
    const float* __restrict__ g3, const float* __restrict__ b3,
    float* __restrict__ ws_w)
{
    const int ch = blockIdx.x;
    float s = 0.f, ss = 0.f;
    for (int b = 0; b < B_; ++b) {
        const float* p = (ch < 64)
            ? ws_r + ((size_t)b * 64 + ch) * N_
            : ws_r + QK_ELEMS + ((size_t)b * C_ + (ch - 64)) * N_;
        for (int i = threadIdx.x; i < N_; i += 256) {
            float v = p[i];
            s += v;
            ss = fmaf(v, v, ss);
        }
    }
    __shared__ float r1[256], r2[256];
    r1[threadIdx.x] = s; r2[threadIdx.x] = ss;
    __syncthreads();
    for (int st = 128; st > 0; st >>= 1) {
        if (threadIdx.x < st) {
            r1[threadIdx.x] += r1[threadIdx.x + st];
            r2[threadIdx.x] += r2[threadIdx.x + st];
        }
        __syncthreads();
    }
    if (threadIdx.x == 0) {
        const float inv = 1.0f / (float)(B_ * N_);
        float mean = r1[0] * inv;
        float var = r2[0] * inv - mean * mean;
        float g, bb;
        if (ch < 32)      { g = g1[ch];      bb = b1[ch]; }
        else if (ch < 64) { g = g2[ch - 32]; bb = b2[ch - 32]; }
        else              { g = g3[ch - 64]; bb = b3[ch - 64]; }
        float scale = g * rsqrtf(var + 1e-5f);
        ws_w[SC_OFF + ch] = scale;
        ws_w[BI_OFF + ch] = bb - scale * mean;
    }
}

// ---------------------------------------------------------------------------
// Kernel 3: in-place relu(sc*y + bi) over qk and d regions.
// ---------------------------------------------------------------------------
__global__ __launch_bounds__(256) void affine_kernel(float* __restrict__ ws)
{
    size_t e = ((size_t)blockIdx.x * 256 + threadIdx.x) * 4;
    int ch;
    if (e < QK_ELEMS) ch = (int)((e >> 12) & 63);
    else              ch = 64 + (int)(((e - QK_ELEMS) >> 12) & 255);
    float s_ = ws[SC_OFF + ch], b_ = ws[BI_OFF + ch];
    float4 v = *(float4*)&ws[e];
    v.x = fmaxf(0.f, s_ * v.x + b_);
    v.y = fmaxf(0.f, s_ * v.y + b_);
    v.z = fmaxf(0.f, s_ * v.z + b_);
    v.w = fmaxf(0.f, s_ * v.w + b_);
    *(float4*)&ws[e] = v;
}

// ---------------------------------------------------------------------------
// Kernel 4: flash attention.  queries = a rows (ch 0..31 of qk), keys = ch
// 32..63 of qk, values = d columns.  TQ=64 queries/block, TK=32 keys/tile.
// out[b][c][m] = x[b][c][m] + sum_n softmax_n(q_m . k_n) * d[c][n]
// Block 256 threads; O-accumulator 64q x 256c, 8q x 8c per thread.
// ---------------------------------------------------------------------------
__global__ __launch_bounds__(256) void flash_kernel(
    const float* __restrict__ x, const float* __restrict__ ws,
    float* __restrict__ out)
{
    __shared__ __align__(16) float Qs[32][68];    // [c][q]
    __shared__ __align__(16) float Ks[32][36];    // [c][kk]
    __shared__ __align__(16) float Dt[32][260];   // [kk][c]
    __shared__ __align__(16) float Sl[32][68];    // [kk][q] scores -> probs
    __shared__ float mArr[64], lArr[64], aArr[64];

    const float* qk = ws;
    const float* dd = ws + QK_ELEMS;
    const int b = blockIdx.y;
    const int n0q = blockIdx.x << 6;
    const int tid = threadIdx.x;

    // stage Q tile once: Qs[c][q] = a[b][c][n0q+q]
    {
        int q = tid & 63, cb = tid >> 6;
#pragma unroll
        for (int i = 0; i < 8; ++i) {
            int c = cb + (i << 2);
            Qs[c][q] = qk[((size_t)b * 64 + c) * N_ + n0q + q];
        }
    }
    if (tid < 64) { mArr[tid] = -1e30f; lArr[tid] = 0.f; }

    float acc[8][8] = {};
    const int qh = tid & 15, kkq = tid >> 4;        // phase A map
    const int qg = tid & 7,  cg  = tid >> 3;        // phase C map
    const int q0a = qh << 2, kk0 = kkq << 1;
    const int q0c = qg << 3, c0 = cg << 3;

    for (int n0k = 0; n0k < N_; n0k += 32) {
        __syncthreads();  // protect Ks/Dt/Sl from previous tile's readers
        // ---- stage K tile: Ks[c][kk] ----
        {
            int c = tid >> 3, jj = (tid & 7) << 2;
            float4 kv = *(const float4*)&qk[((size_t)b * 64 + 32 + c) * N_ + n0k + jj];
            *(float4*)&Ks[c][jj] = kv;
        }
        // ---- stage D tile transposed: Dt[kk][c] ----
        {
            int jj = (tid & 7) << 2, cb2 = tid >> 3;
#pragma unroll
            for (int i = 0; i < 8; ++i) {
                int c = cb2 + (i << 5);
                float4 dv = *(const float4*)&dd[((size_t)b * C_ + c) * N_ + n0k + jj];
                Dt[jj + 0][c] = dv.x;
                Dt[jj + 1][c] = dv.y;
                Dt[jj + 2][c] = dv.z;
                Dt[jj + 3][c] = dv.w;
            }
        }
        __syncthreads();
        // ---- phase A: scores S[q][kk], 4q x 2kk per thread ----
        {
            float s00=0,s10=0,s20=0,s30=0,s01=0,s11=0,s21=0,s31=0;
#pragma unroll
            for (int c = 0; c < 32; ++c) {
                float4 q4 = *(const float4*)&Qs[c][q0a];
                float2 k2 = *(const float2*)&Ks[c][kk0];
                s00 += q4.x*k2.x; s10 += q4.y*k2.x; s20 += q4.z*k2.x; s30 += q4.w*k2.x;
                s01 += q4.x*k2.y; s11 += q4.y*k2.y; s21 += q4.z*k2.y; s31 += q4.w*k2.y;
            }
            float4 v0 = {s00, s10, s20, s30};
            float4 v1 = {s01, s11, s21, s31};
            *(float4*)&Sl[kk0][q0a] = v0;
            *(float4*)&Sl[kk0 + 1][q0a] = v1;
        }
        __syncthreads();
        // ---- phase B: online softmax per query row (one wave) ----
        if (tid < 64) {
            int q = tid;
            float mo = mArr[q];
            float mx = mo;
#pragma unroll
            for (int kk = 0; kk < 32; ++kk) mx = fmaxf(mx, Sl[kk][q]);
            float alpha = __expf(mo - mx);
            float sum = 0.f;
#pragma unroll
            for (int kk = 0; kk < 32; ++kk) {
                float p = __expf(Sl[kk][q] - mx);
                Sl[kk][q] = p;
                sum += p;
            }
            lArr[q] = lArr[q] * alpha + sum;
            mArr[q] = mx;
            aArr[q] = alpha;
        }
        __syncthreads();
        // ---- phase C: rescale + O += P @ D ----
        {
            float al[8];
#pragma unroll
            for (int i = 0; i < 8; ++i) al[i] = aArr[q0c + i];
#pragma unroll
            for (int i = 0; i < 8; ++i)
#pragma unroll
                for (int j = 0; j < 8; ++j) acc[i][j] *= al[i];
#pragma unroll
            for (int kk = 0; kk < 32; ++kk) {
                float4 pa = *(const float4*)&Sl[kk][q0c];
                float4 pb = *(const float4*)&Sl[kk][q0c + 4];
                float4 da = *(const float4*)&Dt[kk][c0];
                float4 db = *(const float4*)&Dt[kk][c0 + 4];
                float pv[8] = {pa.x, pa.y, pa.z, pa.w, pb.x, pb.y, pb.z, pb.w};
                float dv[8] = {da.x, da.y, da.z, da.w, db.x, db.y, db.z, db.w};
#pragma unroll
                for (int i = 0; i < 8; ++i)
#pragma unroll
                    for (int j = 0; j < 8; ++j)
                        acc[i][j] += pv[i] * dv[j];
            }
        }
    }
    // ---- epilogue: out = x + O / l ----
    {
        float linv[8];
#pragma unroll
        for (int i = 0; i < 8; ++i) linv[i] = 1.0f / lArr[q0c + i];
#pragma unroll
        for (int j = 0; j < 8; ++j) {
            int c = c0 + j;
            size_t base = ((size_t)b * C_ + c) * N_ + n0q + q0c;
            float4 x0 = *(const float4*)&x[base];
            float4 x1 = *(const float4*)&x[base + 4];
            float4 o0 = {x0.x + acc[0][j] * linv[0], x0.y + acc[1][j] * linv[1],
                         x0.z + acc[2][j] * linv[2], x0.w + acc[3][j] * linv[3]};
            float4 o1 = {x1.x + acc[4][j] * linv[4], x1.y + acc[5][j] * linv[5],
                         x1.z + acc[6][j] * linv[6], x1.w + acc[7][j] * linv[7]};
            *(float4*)&out[base] = o0;
            *(float4*)&out[base + 4] = o1;
        }
    }
}

extern "C" void kernel_launch(void* const* d_in, const int* in_sizes, int n_in,
                              void* d_out, int out_size, void* d_ws, size_t ws_size,
                              hipStream_t stream) {
    (void)in_sizes; (void)n_in; (void)out_size; (void)ws_size;
    const float* x  = (const float*)d_in[0];
    const float* w1 = (const float*)d_in[1];
    const float* w2 = (const float*)d_in[2];
    const float* w3 = (const float*)d_in[3];
    const float* g1 = (const float*)d_in[4];
    const float* b1 = (const float*)d_in[5];
    const float* g2 = (const float*)d_in[6];
    const float* b2 = (const float*)d_in[7];
    const float* g3 = (const float*)d_in[8];
    const float* b3 = (const float*)d_in[9];
    float* ws = (float*)d_ws;
    float* outp = (float*)d_out;

    ygemm_kernel<<<dim3(256, 5), 256, 0, stream>>>(x, w1, w2, w3, ws);
    stats_kernel<<<320, 256, 0, stream>>>(ws, g1, b1, g2, b2, g3, b3, ws);
    affine_kernel<<<(QK_ELEMS + D_ELEMS) / 4 / 256, 256, 0, stream>>>(ws);
    flash_kernel<<<dim3(N_ / 64, B_), 256, 0, stream>>>(x, ws, outp);
}

// Round 2
// 306.728 us; speedup vs baseline: 2.8304x; 2.8304x over previous
//
#include <hip/hip_runtime.h>
#include <cstddef>
#include <cstdint>

#define B_ 4
#define C_ 256
#define N_ 4096
#define QK_BF 1048576                    /* bf16 elems: [b][64][N] raw y1/y2 -> a,k */
#define D_BF  4194304                    /* bf16 elems: [b][256][N] raw y3 -> d     */
#define D_OFF_B   ((size_t)QK_BF * 2)    /* 2 MB  */
#define SUM_OFF_B (D_OFF_B + (size_t)D_BF * 2)  /* 10 MB: sum[320],sumsq[320],sc[320],bi[320] */

typedef unsigned short bfraw;
typedef __attribute__((ext_vector_type(8))) short short8;
typedef __attribute__((ext_vector_type(4))) float float4v;
typedef __attribute__((ext_vector_type(4))) bfraw bfraw4;

__device__ inline bfraw f2bf(float f) {
    union { float f; uint32_t u; } c; c.f = f;
    uint32_t u = c.u;
    u += 0x7fffu + ((u >> 16) & 1u);     // RNE
    return (bfraw)(u >> 16);
}
__device__ inline float bf2f(bfraw h) {
    union { uint32_t u; float f; } c; c.u = ((uint32_t)h) << 16;
    return c.f;
}

// ---------------------------------------------------------------------------
// Kernel 0: zero the stats accumulators (ws is poisoned 0xAA every launch).
// ---------------------------------------------------------------------------
__global__ void zero_kernel(float* __restrict__ sums) {
    for (int i = threadIdx.x; i < 640; i += 256) sums[i] = 0.f;
}

// ---------------------------------------------------------------------------
// Kernel 1: y = w @ x for all 320 channels; store bf16; accumulate per-channel
// sum/sumsq (fp32 atomics) for BN stats.
// ---------------------------------------------------------------------------
__global__ __launch_bounds__(256) void ygemm_kernel(
    const float* __restrict__ x, const float* __restrict__ w1,
    const float* __restrict__ w2, const float* __restrict__ w3,
    uint8_t* __restrict__ wsb)
{
    __shared__ __align__(16) float Ws[32][68];
    __shared__ __align__(16) float Xs[32][68];
    const int colTile = blockIdx.x;
    const int by = blockIdx.y;
    const int b = (colTile << 6) / N_;
    const int n0 = (colTile << 6) & (N_ - 1);
    const int obase = by << 6;
    const int tx = threadIdx.x & 15, ty = threadIdx.x >> 4;
    const int ckl = threadIdx.x & 31;
    const int olb = threadIdx.x >> 5;
    const int nl  = threadIdx.x & 63;
    const int clb = threadIdx.x >> 6;
    float acc[4][4] = {};

    for (int cb = 0; cb < C_; cb += 32) {
#pragma unroll
        for (int i = 0; i < 8; ++i) {
            int ol = olb + (i << 3);
            int og = obase + ol;
            const float* wr = (og < 32) ? (w1 + og * C_)
                              : (og < 64) ? (w2 + (og - 32) * C_)
                                          : (w3 + (og - 64) * C_);
            Ws[ckl][ol] = wr[cb + ckl];
        }
#pragma unroll
        for (int i = 0; i < 8; ++i) {
            int cl = clb + (i << 2);
            Xs[cl][nl] = x[((size_t)b * C_ + cb + cl) * N_ + n0 + nl];
        }
        __syncthreads();
#pragma unroll
        for (int kk = 0; kk < 32; ++kk) {
            float4 a4 = *(const float4*)&Ws[kk][ty << 2];
            float4 b4 = *(const float4*)&Xs[kk][tx << 2];
            float av[4] = {a4.x, a4.y, a4.z, a4.w};
            float bv[4] = {b4.x, b4.y, b4.z, b4.w};
#pragma unroll
            for (int i = 0; i < 4; ++i)
#pragma unroll
                for (int j = 0; j < 4; ++j)
                    acc[i][j] += av[i] * bv[j];
        }
        __syncthreads();
    }
    bfraw* qkb = (bfraw*)wsb;
    bfraw* db  = (bfraw*)(wsb + D_OFF_B);
    float* sums  = (float*)(wsb + SUM_OFF_B);
    float* sumsq = sums + 320;
#pragma unroll
    for (int i = 0; i < 4; ++i) {
        int og = obase + (ty << 2) + i;
        bfraw4 v = {f2bf(acc[i][0]), f2bf(acc[i][1]), f2bf(acc[i][2]), f2bf(acc[i][3])};
        size_t col = (size_t)n0 + (tx << 2);
        if (og < 64) *(bfraw4*)&qkb[((size_t)b * 64 + og) * N_ + col] = v;
        else         *(bfraw4*)&db[((size_t)b * C_ + (og - 64)) * N_ + col] = v;
        float s  = acc[i][0] + acc[i][1] + acc[i][2] + acc[i][3];
        float ss = acc[i][0]*acc[i][0] + acc[i][1]*acc[i][1]
                 + acc[i][2]*acc[i][2] + acc[i][3]*acc[i][3];
#pragma unroll
        for (int m = 1; m < 16; m <<= 1) {
            s  += __shfl_xor(s, m);
            ss += __shfl_xor(ss, m);
        }
        if (tx == 0) {
            atomicAdd(&sums[og], s);
            atomicAdd(&sumsq[og], ss);
        }
    }
}

// ---------------------------------------------------------------------------
// Kernel 2: finalize BN -> folded scale/bias per channel.
// ---------------------------------------------------------------------------
__global__ void finalize_kernel(
    const float* __restrict__ g1, const float* __restrict__ b1,
    const float* __restrict__ g2, const float* __restrict__ b2,
    const float* __restrict__ g3, const float* __restrict__ b3,
    float* __restrict__ sums)
{
    int ch = threadIdx.x;
    if (ch >= 320) return;
    const float inv = 1.0f / (float)(B_ * N_);
    float mean = sums[ch] * inv;
    float var = sums[320 + ch] * inv - mean * mean;
    float g, bb;
    if (ch < 32)      { g = g1[ch];      bb = b1[ch]; }
    else if (ch < 64) { g = g2[ch - 32]; bb = b2[ch - 32]; }
    else              { g = g3[ch - 64]; bb = b3[ch - 64]; }
    float sc = g * rsqrtf(var + 1e-5f);
    sums[640 + ch] = sc;
    sums[960 + ch] = bb - sc * mean;
}

// ---------------------------------------------------------------------------
// Kernel 3: in-place bf16 relu(sc*y + bi). 8 elems/thread, ch uniform per wave.
// ---------------------------------------------------------------------------
__global__ __launch_bounds__(256) void affine_kernel(uint8_t* __restrict__ wsb)
{
    bfraw* base = (bfraw*)wsb;
    const float* sc = (const float*)(wsb + SUM_OFF_B) + 640;
    const float* bi = sc + 320;
    size_t i8 = ((size_t)blockIdx.x * 256 + threadIdx.x) * 8;
    int ch;
    if (i8 < QK_BF) ch = (int)((i8 >> 12) & 63);
    else            ch = 64 + (int)(((i8 - QK_BF) >> 12) & 255);
    float s = sc[ch], b = bi[ch];
    bfraw4 v0 = *(bfraw4*)&base[i8];
    bfraw4 v1 = *(bfraw4*)&base[i8 + 4];
#pragma unroll
    for (int j = 0; j < 4; ++j) {
        v0[j] = f2bf(fmaxf(0.f, fmaf(s, bf2f(v0[j]), b)));
        v1[j] = f2bf(fmaxf(0.f, fmaf(s, bf2f(v1[j]), b)));
    }
    *(bfraw4*)&base[i8] = v0;
    *(bfraw4*)&base[i8 + 4] = v1;
}

// ---------------------------------------------------------------------------
// Kernel 4: MFMA flash attention.
//   S^T[k][q] = sum_c K[c][k] Q[c][q]   (mfma A=K-frag [k][c], B=Q-frag [c][q])
//   online softmax over k (q lives in lane&15; butterfly over lane-groups)
//   O^T[c][q] += sum_kk D[c][kk] P^T[kk][q]  (A=D-frag direct from global!)
// Block: 256 thr = 4 waves; TQ=64, TK=64; wave w owns q-tile w for softmax and
// c-tiles {w,w+4,w+8,w+12} x all 4 q-tiles for PV.
// ---------------------------------------------------------------------------
__global__ __launch_bounds__(256) void flash_kernel(
    const float* __restrict__ x, const uint8_t* __restrict__ wsb,
    float* __restrict__ out)
{
    const bfraw* qkb = (const bfraw*)wsb;
    const bfraw* db  = (const bfraw*)(wsb + D_OFF_B);
    __shared__ bfraw Klds[64][40];   // [k][c], pad 40
    __shared__ bfraw Qlds[64][40];   // [q][c], pad 40
    __shared__ bfraw Plds[64][72];   // [q][kk], pad 72 (16B-aligned rows)
    __shared__ float alphaLds[64];
    __shared__ float lLds[64];

    const int id  = blockIdx.x;
    const int b   = id & 3;                 // batch on XCDs {b, b+4}
    const int n0q = (id >> 2) << 6;
    const int tid = threadIdx.x;
    const int w   = tid >> 6;
    const int l   = tid & 63;
    const int lq  = l & 15;
    const int lg  = l >> 4;

    const bfraw* qbase = qkb + (size_t)b * 64 * N_;
    const bfraw* kbase = qbase + (size_t)32 * N_;
    const bfraw* dbase = db + (size_t)b * C_ * N_;

    {   // stage Q transposed: Qlds[q][c]
        int c = tid >> 3, qb = (tid & 7) << 3;
        short8 v = *(const short8*)&qbase[(size_t)c * N_ + n0q + qb];
#pragma unroll
        for (int j = 0; j < 8; ++j) Qlds[qb + j][c] = (bfraw)v[j];
    }
    __syncthreads();
    const short8 qfrag = *(const short8*)&Qlds[w * 16 + lq][lg * 8];  // loop-invariant

    float m_run = -1e30f, l_run = 0.f;
    float4v acc[4][4];
#pragma unroll
    for (int i = 0; i < 4; ++i)
#pragma unroll
        for (int j = 0; j < 4; ++j) acc[i][j] = (float4v){0.f, 0.f, 0.f, 0.f};

    for (int n0k = 0; n0k < N_; n0k += 64) {
        __syncthreads();                       // prev iter's K/P consumers done
        {   // stage K transposed: Klds[k][c]
            int c = tid >> 3, kb = (tid & 7) << 3;
            short8 v = *(const short8*)&kbase[(size_t)c * N_ + n0k + kb];
#pragma unroll
            for (int j = 0; j < 8; ++j) Klds[kb + j][c] = (bfraw)v[j];
        }
        __syncthreads();
        // ---- scores: S^T tiles kt=0..3 for q-tile w ----
        float4v st[4];
#pragma unroll
        for (int kt = 0; kt < 4; ++kt) {
            short8 kfrag = *(const short8*)&Klds[kt * 16 + lq][lg * 8];
            float4v z = {0.f, 0.f, 0.f, 0.f};
            st[kt] = __builtin_amdgcn_mfma_f32_16x16x32_bf16(kfrag, qfrag, z, 0, 0, 0);
        }
        // ---- online softmax (per q = w*16 + lq) ----
        float mx = m_run;
#pragma unroll
        for (int kt = 0; kt < 4; ++kt)
#pragma unroll
            for (int r = 0; r < 4; ++r) mx = fmaxf(mx, st[kt][r]);
        mx = fmaxf(mx, __shfl_xor(mx, 16));
        mx = fmaxf(mx, __shfl_xor(mx, 32));
        float alpha = __expf(m_run - mx);
        m_run = mx;
        float rsum = 0.f;
        bfraw4 pk[4];
#pragma unroll
        for (int kt = 0; kt < 4; ++kt)
#pragma unroll
            for (int r = 0; r < 4; ++r) {
                float p = __expf(st[kt][r] - mx);
                rsum += p;
                pk[kt][r] = f2bf(p);
            }
        rsum += __shfl_xor(rsum, 16);
        rsum += __shfl_xor(rsum, 32);
        l_run = l_run * alpha + rsum;
        if (lg == 0) alphaLds[w * 16 + lq] = alpha;
#pragma unroll
        for (int kt = 0; kt < 4; ++kt)
            *(bfraw4*)&Plds[w * 16 + lq][kt * 16 + lg * 4] = pk[kt];
        __syncthreads();                       // P + alpha ready
        // ---- rescale O ----
        float al[4];
#pragma unroll
        for (int qt = 0; qt < 4; ++qt) al[qt] = alphaLds[qt * 16 + lq];
#pragma unroll
        for (int ct = 0; ct < 4; ++ct)
#pragma unroll
            for (int qt = 0; qt < 4; ++qt) {
                acc[ct][qt][0] *= al[qt]; acc[ct][qt][1] *= al[qt];
                acc[ct][qt][2] *= al[qt]; acc[ct][qt][3] *= al[qt];
            }
        // ---- PV: O^T += D * P^T ; A(D)-frags straight from global bf16 ----
#pragma unroll
        for (int s = 0; s < 2; ++s) {
            short8 bfr[4];
#pragma unroll
            for (int qt = 0; qt < 4; ++qt)
                bfr[qt] = *(const short8*)&Plds[qt * 16 + lq][s * 32 + lg * 8];
#pragma unroll
            for (int ct = 0; ct < 4; ++ct) {
                int c = (ct * 4 + w) * 16 + lq;
                short8 afr = *(const short8*)&dbase[(size_t)c * N_ + n0k + s * 32 + lg * 8];
#pragma unroll
                for (int qt = 0; qt < 4; ++qt)
                    acc[ct][qt] = __builtin_amdgcn_mfma_f32_16x16x32_bf16(afr, bfr[qt], acc[ct][qt], 0, 0, 0);
            }
        }
    }
    if (lg == 0) lLds[w * 16 + lq] = l_run;
    __syncthreads();
    float linv[4];
#pragma unroll
    for (int qt = 0; qt < 4; ++qt) linv[qt] = 1.0f / lLds[qt * 16 + lq];
#pragma unroll
    for (int ct = 0; ct < 4; ++ct)
#pragma unroll
        for (int r = 0; r < 4; ++r) {
            int c = (ct * 4 + w) * 16 + lg * 4 + r;   // C/D row = lg*4+r
            size_t base = ((size_t)b * C_ + c) * N_ + n0q;
#pragma unroll
            for (int qt = 0; qt < 4; ++qt) {
                size_t idx = base + qt * 16 + lq;      // C/D col = lq -> coalesced
                out[idx] = x[idx] + acc[ct][qt][r] * linv[qt];
            }
        }
}

extern "C" void kernel_launch(void* const* d_in, const int* in_sizes, int n_in,
                              void* d_out, int out_size, void* d_ws, size_t ws_size,
                              hipStream_t stream) {
    (void)in_sizes; (void)n_in; (void)out_size; (void)ws_size;
    const float* x  = (const float*)d_in[0];
    const float* w1 = (const float*)d_in[1];
    const float* w2 = (const float*)d_in[2];
    const float* w3 = (const float*)d_in[3];
    const float* g1 = (const float*)d_in[4];
    const float* b1 = (const float*)d_in[5];
    const float* g2 = (const float*)d_in[6];
    const float* b2 = (const float*)d_in[7];
    const float* g3 = (const float*)d_in[8];
    const float* b3 = (const float*)d_in[9];
    uint8_t* wsb = (uint8_t*)d_ws;
    float* sums = (float*)(wsb + SUM_OFF_B);
    float* outp = (float*)d_out;

    zero_kernel<<<1, 256, 0, stream>>>(sums);
    ygemm_kernel<<<dim3(256, 5), 256, 0, stream>>>(x, w1, w2, w3, wsb);
    finalize_kernel<<<1, 320, 0, stream>>>(g1, b1, g2, b2, g3, b3, sums);
    affine_kernel<<<(QK_BF + D_BF) / 8 / 256, 256, 0, stream>>>(wsb);
    flash_kernel<<<N_ / 64 * B_, 256, 0, stream>>>(x, wsb, outp);
}

// Round 3
// 293.980 us; speedup vs baseline: 2.9531x; 1.0434x over previous
//
#include <hip/hip_runtime.h>
#include <cstddef>
#include <cstdint>

#define B_ 4
#define C_ 256
#define N_ 4096
#define QK_BF 1048576                    /* bf16 elems: qk_t [b][N][64] (q ch 0..31, k ch 32..63) */
#define D_BF  4194304                    /* bf16 elems: [b][256][N] raw y3 -> d                   */
#define D_OFF_B   ((size_t)QK_BF * 2)    /* 2 MB  */
#define SUM_OFF_B (D_OFF_B + (size_t)D_BF * 2)  /* 10 MB: sum[320],sumsq[320],sc[320],bi[320] */

typedef unsigned short bfraw;
typedef __attribute__((ext_vector_type(8))) short short8;
typedef __attribute__((ext_vector_type(4))) float float4v;
typedef __attribute__((ext_vector_type(4))) bfraw bfraw4;

__device__ inline bfraw f2bf(float f) {
    union { float f; uint32_t u; } c; c.f = f;
    uint32_t u = c.u;
    u += 0x7fffu + ((u >> 16) & 1u);     // RNE
    return (bfraw)(u >> 16);
}
__device__ inline float bf2f(bfraw h) {
    union { uint32_t u; float f; } c; c.u = ((uint32_t)h) << 16;
    return c.f;
}

// ---------------------------------------------------------------------------
// Kernel 0: zero the stats accumulators (ws is poisoned 0xAA every launch).
// ---------------------------------------------------------------------------
__global__ void zero_kernel(float* __restrict__ sums) {
    for (int i = threadIdx.x; i < 640; i += 256) sums[i] = 0.f;
}

// ---------------------------------------------------------------------------
// Kernel 1: y = w @ x for all 320 channels; q/k stored TRANSPOSED bf16
// [b][n][64ch]; d stored [b][256][N] bf16; per-channel sum/sumsq atomics.
// ---------------------------------------------------------------------------
__global__ __launch_bounds__(256) void ygemm_kernel(
    const float* __restrict__ x, const float* __restrict__ w1,
    const float* __restrict__ w2, const float* __restrict__ w3,
    uint8_t* __restrict__ wsb)
{
    __shared__ __align__(16) float Ws[32][68];
    __shared__ __align__(16) float Xs[32][68];
    const int colTile = blockIdx.x;
    const int by = blockIdx.y;
    const int b = (colTile << 6) / N_;
    const int n0 = (colTile << 6) & (N_ - 1);
    const int obase = by << 6;
    const int tx = threadIdx.x & 15, ty = threadIdx.x >> 4;
    const int ckl = threadIdx.x & 31;
    const int olb = threadIdx.x >> 5;
    const int nl  = threadIdx.x & 63;
    const int clb = threadIdx.x >> 6;
    float acc[4][4] = {};

    for (int cb = 0; cb < C_; cb += 32) {
#pragma unroll
        for (int i = 0; i < 8; ++i) {
            int ol = olb + (i << 3);
            int og = obase + ol;
            const float* wr = (og < 32) ? (w1 + og * C_)
                              : (og < 64) ? (w2 + (og - 32) * C_)
                                          : (w3 + (og - 64) * C_);
            Ws[ckl][ol] = wr[cb + ckl];
        }
#pragma unroll
        for (int i = 0; i < 8; ++i) {
            int cl = clb + (i << 2);
            Xs[cl][nl] = x[((size_t)b * C_ + cb + cl) * N_ + n0 + nl];
        }
        __syncthreads();
#pragma unroll
        for (int kk = 0; kk < 32; ++kk) {
            float4 a4 = *(const float4*)&Ws[kk][ty << 2];
            float4 b4 = *(const float4*)&Xs[kk][tx << 2];
            float av[4] = {a4.x, a4.y, a4.z, a4.w};
            float bv[4] = {b4.x, b4.y, b4.z, b4.w};
#pragma unroll
            for (int i = 0; i < 4; ++i)
#pragma unroll
                for (int j = 0; j < 4; ++j)
                    acc[i][j] += av[i] * bv[j];
        }
        __syncthreads();
    }
    bfraw* qkt = (bfraw*)wsb;
    bfraw* db  = (bfraw*)(wsb + D_OFF_B);
    float* sums  = (float*)(wsb + SUM_OFF_B);
    float* sumsq = sums + 320;

    if (by == 0) {
        // transposed store: channel = ty*4+i (0..63), col n = n0+tx*4+j
#pragma unroll
        for (int j = 0; j < 4; ++j) {
            bfraw4 tv = {f2bf(acc[0][j]), f2bf(acc[1][j]),
                         f2bf(acc[2][j]), f2bf(acc[3][j])};
            *(bfraw4*)&qkt[((size_t)(b * N_ + n0 + (tx << 2) + j) << 6) + (ty << 2)] = tv;
        }
    } else {
#pragma unroll
        for (int i = 0; i < 4; ++i) {
            int og64 = (by - 1) * 64 + (ty << 2) + i;
            bfraw4 v = {f2bf(acc[i][0]), f2bf(acc[i][1]), f2bf(acc[i][2]), f2bf(acc[i][3])};
            *(bfraw4*)&db[((size_t)b * C_ + og64) * N_ + n0 + (tx << 2)] = v;
        }
    }
#pragma unroll
    for (int i = 0; i < 4; ++i) {
        int og = obase + (ty << 2) + i;
        float s  = acc[i][0] + acc[i][1] + acc[i][2] + acc[i][3];
        float ss = acc[i][0]*acc[i][0] + acc[i][1]*acc[i][1]
                 + acc[i][2]*acc[i][2] + acc[i][3]*acc[i][3];
#pragma unroll
        for (int m = 1; m < 16; m <<= 1) {
            s  += __shfl_xor(s, m);
            ss += __shfl_xor(ss, m);
        }
        if (tx == 0) {
            atomicAdd(&sums[og], s);
            atomicAdd(&sumsq[og], ss);
        }
    }
}

// ---------------------------------------------------------------------------
// Kernel 2: finalize BN -> folded scale/bias per channel.
// ---------------------------------------------------------------------------
__global__ void finalize_kernel(
    const float* __restrict__ g1, const float* __restrict__ b1,
    const float* __restrict__ g2, const float* __restrict__ b2,
    const float* __restrict__ g3, const float* __restrict__ b3,
    float* __restrict__ sums)
{
    int ch = threadIdx.x;
    if (ch >= 320) return;
    const float inv = 1.0f / (float)(B_ * N_);
    float mean = sums[ch] * inv;
    float var = sums[320 + ch] * inv - mean * mean;
    float g, bb;
    if (ch < 32)      { g = g1[ch];      bb = b1[ch]; }
    else if (ch < 64) { g = g2[ch - 32]; bb = b2[ch - 32]; }
    else              { g = g3[ch - 64]; bb = b3[ch - 64]; }
    float sc = g * rsqrtf(var + 1e-5f);
    sums[640 + ch] = sc;
    sums[960 + ch] = bb - sc * mean;
}

// ---------------------------------------------------------------------------
// Kernel 3: in-place bf16 relu(sc*y + bi).  qk_t region: ch = idx & 63
// (per-element scales); d region: ch uniform per wave.
// ---------------------------------------------------------------------------
__global__ __launch_bounds__(256) void affine_kernel(uint8_t* __restrict__ wsb)
{
    bfraw* base = (bfraw*)wsb;
    const float* sc = (const float*)(wsb + SUM_OFF_B) + 640;
    const float* bi = sc + 320;
    size_t i8 = ((size_t)blockIdx.x * 256 + threadIdx.x) * 8;
    bfraw4 v0 = *(bfraw4*)&base[i8];
    bfraw4 v1 = *(bfraw4*)&base[i8 + 4];
    if (i8 < QK_BF) {
        int ch0 = (int)(i8 & 63);
        float4 s0 = *(const float4*)&sc[ch0];
        float4 s1 = *(const float4*)&sc[ch0 + 4];
        float4 c0 = *(const float4*)&bi[ch0];
        float4 c1 = *(const float4*)&bi[ch0 + 4];
        float sa[8] = {s0.x, s0.y, s0.z, s0.w, s1.x, s1.y, s1.z, s1.w};
        float ca[8] = {c0.x, c0.y, c0.z, c0.w, c1.x, c1.y, c1.z, c1.w};
#pragma unroll
        for (int j = 0; j < 4; ++j) {
            v0[j] = f2bf(fmaxf(0.f, fmaf(sa[j],     bf2f(v0[j]), ca[j])));
            v1[j] = f2bf(fmaxf(0.f, fmaf(sa[j + 4], bf2f(v1[j]), ca[j + 4])));
        }
    } else {
        int ch = 64 + (int)(((i8 - QK_BF) >> 12) & 255);
        float s = sc[ch], b = bi[ch];
#pragma unroll
        for (int j = 0; j < 4; ++j) {
            v0[j] = f2bf(fmaxf(0.f, fmaf(s, bf2f(v0[j]), b)));
            v1[j] = f2bf(fmaxf(0.f, fmaf(s, bf2f(v1[j]), b)));
        }
    }
    *(bfraw4*)&base[i8] = v0;
    *(bfraw4*)&base[i8 + 4] = v1;
}

// ---------------------------------------------------------------------------
// Kernel 4: MFMA flash attention, C-split x2, all MFMA inputs except P come
// straight from global (L2-resident).  Grid 512: id&3=batch, (id>>2)&1=c-half,
// id>>3 = q-tile  ->  each (batch,half) pins one XCD's L2.
// Per iter: 4 score MFMAs (own q-tile) + softmax + P->LDS (XOR-swizzled,
// double-buffered, ONE barrier) + 16 PV MFMAs (2 c-tiles x 4 q-tiles x 2).
// ---------------------------------------------------------------------------
__global__ __launch_bounds__(256, 2) void flash_kernel(
    const float* __restrict__ x, const uint8_t* __restrict__ wsb,
    float* __restrict__ out)
{
    const bfraw* qkt = (const bfraw*)wsb;
    const bfraw* db  = (const bfraw*)(wsb + D_OFF_B);
    __shared__ bfraw Pl[2][64 * 64];     // [q][kk] rows of 64, XOR-swizzled granules
    __shared__ float alphaS[2][64];
    __shared__ float lS[64];

    const int id  = blockIdx.x;
    const int b   = id & 3;
    const int hf  = (id >> 2) & 1;
    const int n0q = (id >> 3) << 6;
    const int tid = threadIdx.x;
    const int w   = tid >> 6;
    const int l   = tid & 63;
    const int lq  = l & 15;
    const int lg  = l >> 4;
    const int sw  = lq & 7;              // XOR swizzle key (row q ≡ lq mod 8)

    const bfraw* qkb   = qkt + ((size_t)b * N_ << 6);
    const bfraw* dbase = db + ((size_t)b * C_ + hf * 128) * N_;

    const short8 qfrag = *(const short8*)&qkb[((size_t)(n0q + w * 16 + lq) << 6) + lg * 8];

    float m_run = -1e30f, l_run = 0.f;
    float4v acc[2][4];
#pragma unroll
    for (int i = 0; i < 2; ++i)
#pragma unroll
        for (int j = 0; j < 4; ++j) acc[i][j] = (float4v){0.f, 0.f, 0.f, 0.f};

    for (int n0k = 0; n0k < N_; n0k += 64) {
        const int ib = (n0k >> 6) & 1;
        // ---- scores S^T[k][q] for q-tile w ----
        float4v st[4];
#pragma unroll
        for (int kt = 0; kt < 4; ++kt) {
            short8 kf = *(const short8*)&qkb[((size_t)(n0k + kt * 16 + lq) << 6) + 32 + lg * 8];
            float4v z = {0.f, 0.f, 0.f, 0.f};
            st[kt] = __builtin_amdgcn_mfma_f32_16x16x32_bf16(kf, qfrag, z, 0, 0, 0);
        }
        // ---- online softmax (q = w*16 + lq) ----
        float mx = m_run;
#pragma unroll
        for (int kt = 0; kt < 4; ++kt)
#pragma unroll
            for (int r = 0; r < 4; ++r) mx = fmaxf(mx, st[kt][r]);
        mx = fmaxf(mx, __shfl_xor(mx, 16));
        mx = fmaxf(mx, __shfl_xor(mx, 32));
        float alpha = __expf(m_run - mx);
        m_run = mx;
        float rsum = 0.f;
        bfraw4 pk[4];
#pragma unroll
        for (int kt = 0; kt < 4; ++kt)
#pragma unroll
            for (int r = 0; r < 4; ++r) {
                float p = __expf(st[kt][r] - mx);
                rsum += p;
                pk[kt][r] = f2bf(p);
            }
        rsum += __shfl_xor(rsum, 16);
        rsum += __shfl_xor(rsum, 32);
        l_run = l_run * alpha + rsum;
        if (lg == 0) alphaS[ib][w * 16 + lq] = alpha;
        // ---- P write, granule-XOR swizzle: addr = q*64 + (g^sw)*8 + sub ----
#pragma unroll
        for (int kt = 0; kt < 4; ++kt) {
            int g = (2 * kt + (lg >> 1)) ^ sw;
            *(bfraw4*)&Pl[ib][(w * 16 + lq) * 64 + g * 8 + (lg & 1) * 4] = pk[kt];
        }
        __syncthreads();
        // ---- rescale O ----
        float al[4];
#pragma unroll
        for (int qt = 0; qt < 4; ++qt) al[qt] = alphaS[ib][qt * 16 + lq];
#pragma unroll
        for (int ct = 0; ct < 2; ++ct)
#pragma unroll
            for (int qt = 0; qt < 4; ++qt) {
                acc[ct][qt][0] *= al[qt]; acc[ct][qt][1] *= al[qt];
                acc[ct][qt][2] *= al[qt]; acc[ct][qt][3] *= al[qt];
            }
        // ---- PV: O^T[c][q] += D P^T ; A(D) direct from global ----
#pragma unroll
        for (int s = 0; s < 2; ++s) {
            short8 bfr[4];
#pragma unroll
            for (int qt = 0; qt < 4; ++qt) {
                int g = (4 * s + lg) ^ sw;
                bfr[qt] = *(const short8*)&Pl[ib][(qt * 16 + lq) * 64 + g * 8];
            }
#pragma unroll
            for (int ct = 0; ct < 2; ++ct) {
                int c = (ct * 4 + w) * 16 + lq;
                short8 afr = *(const short8*)&dbase[(size_t)c * N_ + n0k + s * 32 + lg * 8];
#pragma unroll
                for (int qt = 0; qt < 4; ++qt)
                    acc[ct][qt] = __builtin_amdgcn_mfma_f32_16x16x32_bf16(afr, bfr[qt], acc[ct][qt], 0, 0, 0);
            }
        }
    }
    if (lg == 0) lS[w * 16 + lq] = l_run;
    __syncthreads();
    float linv[4];
#pragma unroll
    for (int qt = 0; qt < 4; ++qt) linv[qt] = 1.0f / lS[qt * 16 + lq];
#pragma unroll
    for (int ct = 0; ct < 2; ++ct)
#pragma unroll
        for (int r = 0; r < 4; ++r) {
            int c = hf * 128 + (ct * 4 + w) * 16 + lg * 4 + r;
            size_t base = ((size_t)b * C_ + c) * N_ + n0q;
#pragma unroll
            for (int qt = 0; qt < 4; ++qt) {
                size_t idx = base + qt * 16 + lq;
                out[idx] = x[idx] + acc[ct][qt][r] * linv[qt];
            }
        }
}

extern "C" void kernel_launch(void* const* d_in, const int* in_sizes, int n_in,
                              void* d_out, int out_size, void* d_ws, size_t ws_size,
                              hipStream_t stream) {
    (void)in_sizes; (void)n_in; (void)out_size; (void)ws_size;
    const float* x  = (const float*)d_in[0];
    const float* w1 = (const float*)d_in[1];
    const float* w2 = (const float*)d_in[2];
    const float* w3 = (const float*)d_in[3];
    const float* g1 = (const float*)d_in[4];
    const float* b1 = (const float*)d_in[5];
    const float* g2 = (const float*)d_in[6];
    const float* b2 = (const float*)d_in[7];
    const float* g3 = (const float*)d_in[8];
    const float* b3 = (const float*)d_in[9];
    uint8_t* wsb = (uint8_t*)d_ws;
    float* sums = (float*)(wsb + SUM_OFF_B);
    float* outp = (float*)d_out;

    zero_kernel<<<1, 256, 0, stream>>>(sums);
    ygemm_kernel<<<dim3(256, 5), 256, 0, stream>>>(x, w1, w2, w3, wsb);
    finalize_kernel<<<1, 320, 0, stream>>>(g1, b1, g2, b2, g3, b3, sums);
    affine_kernel<<<(QK_BF + D_BF) / 8 / 256, 256, 0, stream>>>(wsb);
    flash_kernel<<<N_ / 64 * B_ * 2, 256, 0, stream>>>(x, wsb, outp);
}